// Round 5
// baseline (16.463 us; speedup 1.0000x reference)
//
#include <hip/hip_runtime.h>
#include <math.h>

// out[b,q] = T_q(xmean_b) * inner_sum[b,q]/IN
//   inner_sum[b,q] = sum_p c[q]*sin(pi*(q+1)*x[b,p])*W[q,p]
//   xmean_b = (1/D) sum_q tanh(inner_sum[b,q]);  T_q(x)=cos(q*acos(x)), |xmean|<1
// theta input dead (corr == 0). sin in REVOLUTIONS: sin(pi*k*x) = v_sin((k/2)*x).
// cw4[p4][q]: transposed so lane-indexed-by-q reads are contiguous ds_read_b128.
// 512 blocks x 512 thr = 2 blocks/CU, 16 waves/CU: prologue of one block
// overlaps main loop of the other; 4 waves/SIMD hides LDS/trans latency.

#define IN_DIM 100
#define MAXD   100
#define NP4    (IN_DIM / 4)     // 25
#define WAVES  8
#define BLK    (WAVES * 64)     // 512 threads
#define ROWS   WAVES            // 1 row per wave
#define INV2PI 0.15915494309189535f

__device__ __forceinline__ float fast_tanh(float v) {
    float e = __expf(2.0f * v);
    return 1.0f - 2.0f / (e + 1.0f);
}

__global__ __launch_bounds__(BLK) void kat_kernel(
    const float* __restrict__ x, const float* __restrict__ W,
    const int* __restrict__ dimp, float* __restrict__ out, int B)
{
    const int D = *dimp;
    const int P = (IN_DIM < D) ? IN_DIM : D;

    __shared__ float4 cw4[NP4][MAXD];      // 40 KB, [p4][q]
    __shared__ float  xr[ROWS][IN_DIM];    // 3.2 KB, row stride 400B (16B aligned)

    const int t = threadIdx.x;
    const int row0 = blockIdx.x * ROWS;

    {   // stage x rows (float4)
        const float4* x4 = (const float4*)(x + (size_t)row0 * IN_DIM);
        for (int i = t; i < ROWS * NP4; i += BLK) {
            int r = i / NP4;
            int p = (i - r * NP4) * 4;
            float4 v = (row0 + r < B) ? x4[i] : make_float4(0.f, 0.f, 0.f, 0.f);
            xr[r][p] = v.x; xr[r][p+1] = v.y; xr[r][p+2] = v.z; xr[r][p+3] = v.w;
        }
    }
    // stage cw4 = cq[q] * W[q][4p4..4p4+3]; rows q>=D / cols p>=P zeroed
    for (int idx = t; idx < NP4 * MAXD; idx += BLK) {
        int p4 = idx / MAXD;
        int q  = idx - p4 * MAXD;
        float k = (float)(q + 1);
        float c;
        if (q < 15) {
            c = 1.0f / k;
        } else {
            float qf = (float)q;
            float S = 1.0f + 0.2f * __logf(qf / 15.0f) * (1.0f - __expf(-0.03f * (qf - 15.0f)));
            c = 1.0f / (k * S);
        }
        c = (q < D) ? c * __expf(-0.03f * k * k) : 0.0f;
        float4 wv = ((const float4*)W)[q * (MAXD / 4) + p4];
        int p = 4 * p4;
        float4 v;
        v.x = (p     < P) ? c * wv.x : 0.0f;
        v.y = (p + 1 < P) ? c * wv.y : 0.0f;
        v.z = (p + 2 < P) ? c * wv.z : 0.0f;
        v.w = (p + 3 < P) ? c * wv.w : 0.0f;
        cw4[p4][q] = v;
    }
    __syncthreads();

    const int w    = t >> 6;
    const int lane = t & 63;
    const int b    = row0 + w;

    const int q0  = lane;
    const int q1  = lane + 64;
    const int q1c = (q1 < MAXD - 1) ? q1 : (MAXD - 1);   // clamp; masked below
    const float m1 = (q1 < D) ? 1.0f : 0.0f;

    const float f0 = 0.5f * (float)(q0 + 1);  // revolutions
    const float f1 = 0.5f * (float)(q1 + 1);

    const float4* __restrict__ xw4 = (const float4*)&xr[w][0];

    float a0 = 0.0f, a1 = 0.0f;
    #pragma unroll 5
    for (int p4 = 0; p4 < NP4; ++p4) {
        float4 xv = xw4[p4];            // wave-uniform LDS broadcast (b128)
        float4 c0 = cw4[p4][q0];        // lane-contiguous ds_read_b128
        float4 c1 = cw4[p4][q1c];

        a0 = fmaf(__builtin_amdgcn_sinf(f0 * xv.x), c0.x, a0);
        a1 = fmaf(__builtin_amdgcn_sinf(f1 * xv.x), c1.x, a1);
        a0 = fmaf(__builtin_amdgcn_sinf(f0 * xv.y), c0.y, a0);
        a1 = fmaf(__builtin_amdgcn_sinf(f1 * xv.y), c1.y, a1);
        a0 = fmaf(__builtin_amdgcn_sinf(f0 * xv.z), c0.z, a0);
        a1 = fmaf(__builtin_amdgcn_sinf(f1 * xv.z), c1.z, a1);
        a0 = fmaf(__builtin_amdgcn_sinf(f0 * xv.w), c0.w, a0);
        a1 = fmaf(__builtin_amdgcn_sinf(f1 * xv.w), c1.w, a1);
    }
    a1 *= m1;                           // kill clamped-row garbage (q1 >= D)

    // q>=D rows staged zero -> tanh(0)=0
    float s = fast_tanh(a0) + fast_tanh(a1);
    #pragma unroll
    for (int m = 32; m; m >>= 1) s += __shfl_xor(s, m);

    const float thr = acosf(s / (float)D) * INV2PI;
    const float inv = 1.0f / (float)IN_DIM;
    if (b < B) {
        if (q0 < D) out[b * D + q0] = __builtin_amdgcn_cosf((float)q0 * thr) * a0 * inv;
        if (q1 < D) out[b * D + q1] = __builtin_amdgcn_cosf((float)q1 * thr) * a1 * inv;
    }
}

extern "C" void kernel_launch(void* const* d_in, const int* in_sizes, int n_in,
                              void* d_out, int out_size, void* d_ws, size_t ws_size,
                              hipStream_t stream) {
    const float* x    = (const float*)d_in[0];
    const float* W    = (const float*)d_in[1];
    // d_in[2] = theta (unused: corr == 0)
    const int*   dimp = (const int*)d_in[3];
    float*       out  = (float*)d_out;

    const int B = in_sizes[0] / IN_DIM;          // 4096
    const int grid = (B + ROWS - 1) / ROWS;      // 512 blocks x 512 threads = 2/CU

    hipLaunchKernelGGL(kat_kernel, dim3(grid), dim3(BLK), 0, stream,
                       x, W, dimp, out, B);
}

// Round 6
// 14.814 us; speedup vs baseline: 1.1113x; 1.1113x over previous
//
#include <hip/hip_runtime.h>
#include <math.h>

// out[b,q] = T_q(xmean_b) * inner_sum[b,q]/IN
//   inner_sum[b,q] = sum_p c[q]*sin(pi*(q+1)*x[b,p])*W[q,p]
//   xmean_b = (1/D) sum_q tanh(inner_sum[b,q]);  T_q(x)=cos(q*acos(x)), |xmean|<1
// theta input dead (corr == 0). sin in REVOLUTIONS: sin(pi*k*x) = v_sin((k/2)*x).
//
// Layout: cwA[p4][l] = cq[l]*W[l][4p4..], cwB[p4][l] = cq[l+64]*W[l+64][..] (zero-padded
// past row 99) -> both inner-loop ds_read_b128 are lane-contiguous, no clamp/mask VALU.
// 256 blocks x 1024 thr, ~58 KB LDS -> 2 blocks/CU; __launch_bounds__(1024,8) pins
// VGPR<=64 so all 32 waves/CU are resident (R3 vs R4/R5 showed occupancy is the lever).

#define IN_DIM 100
#define MAXD   100
#define NP4    (IN_DIM / 4)     // 25
#define WAVES  16
#define BLK    (WAVES * 64)     // 1024 threads
#define ROWS   WAVES            // 1 batch row per wave
#define INV2PI 0.15915494309189535f

__device__ __forceinline__ float fast_tanh(float v) {
    float e = __expf(2.0f * v);
    return 1.0f - 2.0f / (e + 1.0f);
}

__global__ __launch_bounds__(BLK, 8) void kat_kernel(
    const float* __restrict__ x, const float* __restrict__ W,
    const int* __restrict__ dimp, float* __restrict__ out, int B)
{
    const int D = *dimp;
    const int P = (IN_DIM < D) ? IN_DIM : D;

    __shared__ float4 cwA[NP4][64];        // rows q = 0..63        (25.6 KB)
    __shared__ float4 cwB[NP4][64];        // rows q = 64..127, zero-padded >=MAXD (25.6 KB)
    __shared__ float  xr[ROWS][IN_DIM];    // 6.4 KB

    const int t = threadIdx.x;
    const int row0 = blockIdx.x * ROWS;

    {   // stage x rows (float4-coalesced)
        const float4* x4 = (const float4*)(x + (size_t)row0 * IN_DIM);
        for (int i = t; i < ROWS * NP4; i += BLK) {
            int r = i / NP4;
            int p = (i - r * NP4) * 4;
            float4 v = (row0 + r < B) ? x4[i] : make_float4(0.f, 0.f, 0.f, 0.f);
            xr[r][p] = v.x; xr[r][p+1] = v.y; xr[r][p+2] = v.z; xr[r][p+3] = v.w;
        }
    }
    // stage cwA/cwB = cq[q]*W[q][4p4..4p4+3]; q>=D or p>=P -> 0
    for (int idx = t; idx < NP4 * 128; idx += BLK) {
        int p4 = idx / 128;
        int q  = idx - p4 * 128;           // 0..127
        float4 v = make_float4(0.f, 0.f, 0.f, 0.f);
        if (q < MAXD && q < D) {
            float k = (float)(q + 1);
            float c;
            if (q < 15) {
                c = 1.0f / k;
            } else {
                float qf = (float)q;
                float S = 1.0f + 0.2f * __logf(qf / 15.0f) * (1.0f - __expf(-0.03f * (qf - 15.0f)));
                c = 1.0f / (k * S);
            }
            c *= __expf(-0.03f * k * k);
            float4 wv = ((const float4*)W)[q * (MAXD / 4) + p4];
            int p = 4 * p4;
            v.x = (p     < P) ? c * wv.x : 0.0f;
            v.y = (p + 1 < P) ? c * wv.y : 0.0f;
            v.z = (p + 2 < P) ? c * wv.z : 0.0f;
            v.w = (p + 3 < P) ? c * wv.w : 0.0f;
        }
        if (q < 64) cwA[p4][q]      = v;
        else        cwB[p4][q - 64] = v;
    }
    __syncthreads();

    const int w    = t >> 6;
    const int lane = t & 63;
    const int b    = row0 + w;

    const int q0 = lane;
    const int q1 = lane + 64;

    const float f0 = 0.5f * (float)(q0 + 1);  // revolutions: sin(pi*k*x)=sin2pi((k/2)x)
    const float f1 = 0.5f * (float)(q1 + 1);

    const float4* __restrict__ xw4 = (const float4*)&xr[w][0];

    float a0 = 0.0f, a1 = 0.0f;
    for (int p4 = 0; p4 < NP4; ++p4) {
        float4 xv = xw4[p4];            // wave-uniform LDS broadcast (b128)
        float4 c0 = cwA[p4][lane];      // lane-contiguous ds_read_b128
        float4 c1 = cwB[p4][lane];      // zero rows for q>=D -> no masking needed

        a0 = fmaf(__builtin_amdgcn_sinf(f0 * xv.x), c0.x, a0);
        a1 = fmaf(__builtin_amdgcn_sinf(f1 * xv.x), c1.x, a1);
        a0 = fmaf(__builtin_amdgcn_sinf(f0 * xv.y), c0.y, a0);
        a1 = fmaf(__builtin_amdgcn_sinf(f1 * xv.y), c1.y, a1);
        a0 = fmaf(__builtin_amdgcn_sinf(f0 * xv.z), c0.z, a0);
        a1 = fmaf(__builtin_amdgcn_sinf(f1 * xv.z), c1.z, a1);
        a0 = fmaf(__builtin_amdgcn_sinf(f0 * xv.w), c0.w, a0);
        a1 = fmaf(__builtin_amdgcn_sinf(f1 * xv.w), c1.w, a1);
    }

    // q>=D contributions are exactly 0 (zero-staged rows); tanh(0)=0
    float s = fast_tanh(a0) + fast_tanh(a1);
    #pragma unroll
    for (int m = 32; m; m >>= 1) s += __shfl_xor(s, m);

    const float thr = acosf(s / (float)D) * INV2PI;
    const float inv = 1.0f / (float)IN_DIM;
    if (b < B) {
        if (q0 < D) out[b * D + q0] = __builtin_amdgcn_cosf((float)q0 * thr) * a0 * inv;
        if (q1 < D) out[b * D + q1] = __builtin_amdgcn_cosf((float)q1 * thr) * a1 * inv;
    }
}

extern "C" void kernel_launch(void* const* d_in, const int* in_sizes, int n_in,
                              void* d_out, int out_size, void* d_ws, size_t ws_size,
                              hipStream_t stream) {
    const float* x    = (const float*)d_in[0];
    const float* W    = (const float*)d_in[1];
    // d_in[2] = theta (unused: corr == 0)
    const int*   dimp = (const int*)d_in[3];
    float*       out  = (float*)d_out;

    const int B = in_sizes[0] / IN_DIM;          // 4096
    const int grid = (B + ROWS - 1) / ROWS;      // 256 blocks x 1024 threads

    hipLaunchKernelGGL(kat_kernel, dim3(grid), dim3(BLK), 0, stream,
                       x, W, dimp, out, B);
}